// Round 9
// baseline (272.139 us; speedup 1.0000x reference)
//
#include <hip/hip_runtime.h>

#define BLOCK 256
#define NWAVES (BLOCK / 64)
#define GRID 768   // 3 blocks/CU x 256 CUs: fully resident (LDS-bound), persistent

// Native clang vector: bit-identical to float4, usable with builtins.
typedef float f32x4 __attribute__((ext_vector_type(4)));

// ln(x) via v_log_f32 (log2, ~1 ulp) * ln2. Inputs >= ~5e-3; output absmax
// budget 0.675 on values up to ~454 -> ~1.5e-3 relative; these are ~1e-7.
__device__ __forceinline__ float fast_ln(float x) {
    return 0.69314718056f * __builtin_amdgcn_logf(x);
}
__device__ __forceinline__ float fast_rcp(float x) {
    return __builtin_amdgcn_rcpf(x);
}
__device__ __forceinline__ float fast_rsq(float x) {
    return __builtin_amdgcn_rsqf(x);
}

// ds_bpermute_b32 crossbar gather of the lane-resident parameter table;
// N_RELS == 64 == wavefront. Execute only with all 64 lanes active.
__device__ __forceinline__ float bperm(int ab, float v) {
    return __int_as_float(__builtin_amdgcn_ds_bpermute(ab, __float_as_int(v)));
}

// Async global->LDS DMA, 16 B/lane. LDS dest = wave-uniform base + lane*16
// (linear); global src is per-lane. Tracked by vmcnt (in-order retirement).
__device__ __forceinline__ void gload_lds16(const float* g, float* l) {
    __builtin_amdgcn_global_load_lds(
        (const __attribute__((address_space(1))) unsigned int*)g,
        (__attribute__((address_space(3))) unsigned int*)l,
        16, 0, 0);
}

// Faithful sparsemax for d=3 (Martins & Astudillo 2016): sort desc, cumsum,
// ksup = sum of support booleans, tau = (cs[ksup-1]-1)/ksup, max(z-tau,0).
__device__ __forceinline__ void sparsemax3(float z0, float z1, float z2,
                                           float& o0, float& o1, float& o2) {
    float lo01 = fminf(z0, z1), hi01 = fmaxf(z0, z1);
    float s2 = fminf(lo01, z2);          // min of all
    float mx = fmaxf(lo01, z2);
    float s0 = fmaxf(hi01, mx);          // max of all
    float s1 = fminf(hi01, mx);          // middle
    float cs2 = s0 + s1;
    float cs3 = cs2 + s2;
    bool k2 = (1.0f + 2.0f * s1 > cs2);
    bool k3 = (1.0f + 3.0f * s2 > cs3);
    int k = 1 + (int)k2 + (int)k3;
    float csk = (k == 1) ? s0 : ((k == 2) ? cs2 : cs3);
    float rk  = (k == 1) ? 1.0f : ((k == 2) ? 0.5f : 0.33333334f);
    float tau = (csk - 1.0f) * rk;
    o0 = fmaxf(z0 - tau, 0.0f);
    o1 = fmaxf(z1 - tau, 0.0f);
    o2 = fmaxf(z2 - tau, 0.0f);
}

__device__ __forceinline__ void edge_core(
    float p0, float p1, float p2,
    float q0, float q1, float q2,
    float m00, float m01, float m02,
    float m10, float m11, float m12,
    float m20, float m21, float m22,
    float b0, float b1, float b2,
    float zeps, float sf,
    float& a0o, float& a1o, float& a2o)
{
    float c0 = m00 * q0 + m01 * q1 + m02 * q2;
    float c1 = m10 * q0 + m11 * q1 + m12 * q2;
    float c2 = m20 * q0 + m21 * q1 + m22 * q2;
    sparsemax3(c0, c1, c2, c0, c1, c2);
    // Reference applies sparsemax to c twice; exactly idempotent projection,
    // second application changes ~ulp. Dropped.
    sparsemax3(p0, p1, p2, p0, p1, p2);
    float a0 = p0 + b0 * (c0 - p0);
    float a1 = p1 + b1 * (c1 - p1);
    float a2 = p2 + b2 * (c2 - p2);
    float z0 = fmaxf(p0 + c0, zeps);
    float z1 = fmaxf(p1 + c1, zeps);
    float z2 = fmaxf(p2 + c2, zeps);
    float rs = fast_rcp(z0 + z1 + z2);
    z0 *= rs; z1 *= rs; z2 *= rs;
    float ent = -(z0 * fast_ln(z0) + z1 * fast_ln(z1) + z2 * fast_ln(z2));
    float dot = p0 * c0 + p1 * c1 + p2 * c2;
    float pp = p0 * p0 + p1 * p1 + p2 * p2;
    float cc = c0 * c0 + c1 * c1 + c2 * c2;
    float cosv = 0.1f + dot * fast_rsq(fmaxf(pp * cc, 1e-20f));
    float scale = sf * cosv * fast_rcp(ent);
    a0o = fmaxf(a0 * scale, 0.001f);
    a1o = fmaxf(a1 * scale, 0.001f);
    a2o = fmaxf(a2 * scale, 0.001f);
}

// __launch_bounds__(256, 3): 3 waves/EU (12 waves/CU) matches the LDS bound
// (48 KB/block -> 3 blocks/CU); lets the allocator use VGPRs freely up to
// ~170 without cutting occupancy below the LDS limit.
__global__ __launch_bounds__(BLOCK, 3) void alpha_kernel(
    const float* __restrict__ prnt, const float* __restrict__ child,
    const float* __restrict__ Mg, const float* __restrict__ betag,
    const float* __restrict__ zeps_p, const float* __restrict__ sf_p,
    const int* __restrict__ rels, float* __restrict__ out, int n_edges)
{
    // Double-buffered per-wave-private staging: buffer b, wave w owns
    // sP[b][w*768..] / sC[b][w*768..] (3 KB each). 48 KB/block total.
    // No __syncthreads anywhere — ordering is per-wave s_waitcnt only.
    __shared__ __align__(16) float sP[2][NWAVES * 768];
    __shared__ __align__(16) float sC[2][NWAVES * 768];

    const int tid  = threadIdx.x;
    const int lane = tid & 63;
    const int w    = tid >> 6;

    // Lane-resident parameter table: lane l holds M[l] (9 regs) + beta[l].
    // Persistent grid: amortized over ~11 chunks (44 edges/thread).
    float mt[9], bt[3];
    {
        const float* mr = Mg + lane * 9;
#pragma unroll
        for (int k = 0; k < 9; ++k) mt[k] = mr[k];
        const float* br = betag + lane * 3;
#pragma unroll
        for (int k = 0; k < 3; ++k) bt[k] = br[k];
    }

    const float zeps = zeps_p[0];
    const float sf   = sf_p[0];
    const int nt4 = n_edges >> 2;            // 4 edges per thread per chunk

    if (nt4 > 0) {
        const int NT4F = 3 * nt4;            // total full float4s per array
        const int S    = GRID * BLOCK;       // chunk stride (threads)
        const int t0   = blockIdx.x * BLOCK + tid;
        const int wt0  = blockIdx.x * BLOCK + (w << 6);  // wave's thread 0
        const int iters = (nt4 + S - 1) / S; // UNIFORM grid-wide: all branches
                                             // below are wave-uniform, so
                                             // bpermute always has 64 lanes.

        // Dense staging of chunk k into buffer b: instr j covers 1024
        // contiguous bytes = 16 full lines. Clamped (dup loads; stores
        // are guarded). 6 vmcnt ops per call.
        auto stage = [&](int k, int b) {
            const int base3 = 3 * (wt0 + k * S);
            float* lp = &sP[b][w * 768];
            float* lc = &sC[b][w * 768];
#pragma unroll
            for (int j = 0; j < 3; ++j) {
                int g = min(base3 + j * 64 + lane, NT4F - 1);
                gload_lds16(prnt  + 4 * g, lp + j * 256);
                gload_lds16(child + 4 * g, lc + j * 256);
            }
        };

        // Prologue. rels load FIRST, then the 6 staging DMAs: the compiler's
        // register-dependency wait for rnext then permits 6 outstanding.
        int4 rnext = ((const int4*)rels)[min(t0, nt4 - 1)];
        stage(0, 0);

        int cur = 0;
        for (int k = 0; k < iters; ++k) {
            const int4 rcur = rnext;
            const bool more = (k + 1 < iters);           // uniform
            if (more) {
                // Issue chunk k+1 (1 rels load + 6 LDS-DMAs = 7 vmcnt ops)
                // BEFORE waiting on chunk k: they fly under k's compute.
                rnext = ((const int4*)rels)[min(t0 + (k + 1) * S, nt4 - 1)];
                stage(k + 1, cur ^ 1);
            }
            // vmcnt retires in issue order: <=7 outstanding means everything
            // older than chunk k+1's 7 ops (i.e. all of chunk k's staging,
            // and chunk k-1's 3 stores) has landed.
            if (more) asm volatile("s_waitcnt vmcnt(7)" ::: "memory");
            else      asm volatile("s_waitcnt vmcnt(0)" ::: "memory");

            float* lp = &sP[cur][w * 768];
            float* lc = &sC[cur][w * 768];

            // Thread's 4 edges = 48 B at byte offset lane*48: 3x ds_read_b128.
            f32x4 pa = *(const f32x4*)(lp + lane * 12);
            f32x4 pb = *(const f32x4*)(lp + lane * 12 + 4);
            f32x4 pc = *(const f32x4*)(lp + lane * 12 + 8);
            f32x4 ca = *(const f32x4*)(lc + lane * 12);
            f32x4 cb = *(const f32x4*)(lc + lane * 12 + 4);
            f32x4 cc = *(const f32x4*)(lc + lane * 12 + 8);

            float P[12] = {pa.x, pa.y, pa.z, pa.w, pb.x, pb.y, pb.z, pb.w,
                           pc.x, pc.y, pc.z, pc.w};
            float C[12] = {ca.x, ca.y, ca.z, ca.w, cb.x, cb.y, cb.z, cb.w,
                           cc.x, cc.y, cc.z, cc.w};
            int R[4] = {rcur.x, rcur.y, rcur.z, rcur.w};
            float O[12];
#pragma unroll
            for (int e = 0; e < 4; ++e) {
                int ab = R[e] << 2;          // byte index for bpermute
                float g0 = bperm(ab, mt[0]), g1 = bperm(ab, mt[1]), g2 = bperm(ab, mt[2]);
                float g3 = bperm(ab, mt[3]), g4 = bperm(ab, mt[4]), g5 = bperm(ab, mt[5]);
                float g6 = bperm(ab, mt[6]), g7 = bperm(ab, mt[7]), g8 = bperm(ab, mt[8]);
                float h0 = bperm(ab, bt[0]), h1 = bperm(ab, bt[1]), h2 = bperm(ab, bt[2]);
                edge_core(P[3 * e], P[3 * e + 1], P[3 * e + 2],
                          C[3 * e], C[3 * e + 1], C[3 * e + 2],
                          g0, g1, g2, g3, g4, g5, g6, g7, g8,
                          h0, h1, h2, zeps, sf,
                          O[3 * e], O[3 * e + 1], O[3 * e + 2]);
            }

            // Output transpose through buf[cur]'s sP region (dead after the
            // ds_reads above; chunk k+1 is staging into buf[cur^1], and
            // chunk k+2's staging into buf[cur] is only issued after these
            // transpose reads are consumed by the stores below).
            *(f32x4*)(lp + lane * 12)     = f32x4{O[0], O[1], O[2],  O[3]};
            *(f32x4*)(lp + lane * 12 + 4) = f32x4{O[4], O[5], O[6],  O[7]};
            *(f32x4*)(lp + lane * 12 + 8) = f32x4{O[8], O[9], O[10], O[11]};
            asm volatile("s_waitcnt lgkmcnt(0)" ::: "memory");

            // Dense stores (regular, cached: nt was neutral-to-worse in r8).
            // Guard g < NT4F excludes OOB threads' garbage slots.
            const int base3 = 3 * (wt0 + k * S);
#pragma unroll
            for (int j = 0; j < 3; ++j) {
                int g = base3 + j * 64 + lane;
                if (g < NT4F) {
                    f32x4 v = *(const f32x4*)(lp + j * 256 + lane * 4);
                    *(f32x4*)(out + 4 * g) = v;
                }
            }
            cur ^= 1;
        }
    }

    // Defensive scalar tail for n_edges % 4 (none at N=8M). Divergent:
    // no cross-lane ops — read M/beta straight from global.
    if (blockIdx.x == 0 && threadIdx.x == 0) {
        for (int e = (n_edges >> 2) * 4; e < n_edges; ++e) {
            int r = rels[e];
            const float* m = Mg + r * 9;
            const float* b = betag + r * 3;
            float a0, a1, a2;
            edge_core(prnt[3 * e], prnt[3 * e + 1], prnt[3 * e + 2],
                      child[3 * e], child[3 * e + 1], child[3 * e + 2],
                      m[0], m[1], m[2], m[3], m[4], m[5], m[6], m[7], m[8],
                      b[0], b[1], b[2], zeps, sf, a0, a1, a2);
            out[3 * e] = a0; out[3 * e + 1] = a1; out[3 * e + 2] = a2;
        }
    }
}

extern "C" void kernel_launch(void* const* d_in, const int* in_sizes, int n_in,
                              void* d_out, int out_size, void* d_ws, size_t ws_size,
                              hipStream_t stream) {
    const float* prnt  = (const float*)d_in[0];
    const float* child = (const float*)d_in[1];
    const float* Mg    = (const float*)d_in[2];
    const float* betag = (const float*)d_in[3];
    const float* zeps  = (const float*)d_in[4];
    const float* sf    = (const float*)d_in[5];
    const int*   rels  = (const int*)d_in[6];
    float* out = (float*)d_out;

    int n_edges = in_sizes[0] / 3;
    alpha_kernel<<<GRID, BLOCK, 0, stream>>>(
        prnt, child, Mg, betag, zeps, sf, rels, out, n_edges);
}

// Round 10
// 264.768 us; speedup vs baseline: 1.0278x; 1.0278x over previous
//
#include <hip/hip_runtime.h>

#define BLOCK 256
#define NWAVES (BLOCK / 64)

// Native clang vector: bit-identical to float4, usable with builtins.
typedef float f32x4 __attribute__((ext_vector_type(4)));

// ln(x) via v_log_f32 (log2, ~1 ulp) * ln2. Inputs >= ~5e-3; output absmax
// budget 0.675 on values up to ~454 -> ~1.5e-3 relative; these are ~1e-7.
__device__ __forceinline__ float fast_ln(float x) {
    return 0.69314718056f * __builtin_amdgcn_logf(x);
}
__device__ __forceinline__ float fast_rcp(float x) {
    return __builtin_amdgcn_rcpf(x);
}
__device__ __forceinline__ float fast_rsq(float x) {
    return __builtin_amdgcn_rsqf(x);
}

// ds_bpermute_b32 crossbar gather of the lane-resident parameter table;
// N_RELS == 64 == wavefront. Execute only with all 64 lanes active.
__device__ __forceinline__ float bperm(int ab, float v) {
    return __int_as_float(__builtin_amdgcn_ds_bpermute(ab, __float_as_int(v)));
}

// Async global->LDS DMA, 16 B/lane. LDS dest = wave-uniform base + lane*16
// (linear); global src is per-lane. Tracked by vmcnt; ZERO VGPR cost — the
// lever that lets us raise in-flight ops/wave without the r5 VGPR collapse.
__device__ __forceinline__ void gload_lds16(const float* g, float* l) {
    __builtin_amdgcn_global_load_lds(
        (const __attribute__((address_space(1))) unsigned int*)g,
        (__attribute__((address_space(3))) unsigned int*)l,
        16, 0, 0);
}

// Faithful sparsemax for d=3 (Martins & Astudillo 2016): sort desc, cumsum,
// ksup = sum of support booleans, tau = (cs[ksup-1]-1)/ksup, max(z-tau,0).
__device__ __forceinline__ void sparsemax3(float z0, float z1, float z2,
                                           float& o0, float& o1, float& o2) {
    float lo01 = fminf(z0, z1), hi01 = fmaxf(z0, z1);
    float s2 = fminf(lo01, z2);          // min of all
    float mx = fmaxf(lo01, z2);
    float s0 = fmaxf(hi01, mx);          // max of all
    float s1 = fminf(hi01, mx);          // middle
    float cs2 = s0 + s1;
    float cs3 = cs2 + s2;
    bool k2 = (1.0f + 2.0f * s1 > cs2);
    bool k3 = (1.0f + 3.0f * s2 > cs3);
    int k = 1 + (int)k2 + (int)k3;
    float csk = (k == 1) ? s0 : ((k == 2) ? cs2 : cs3);
    float rk  = (k == 1) ? 1.0f : ((k == 2) ? 0.5f : 0.33333334f);
    float tau = (csk - 1.0f) * rk;
    o0 = fmaxf(z0 - tau, 0.0f);
    o1 = fmaxf(z1 - tau, 0.0f);
    o2 = fmaxf(z2 - tau, 0.0f);
}

__device__ __forceinline__ void edge_core(
    float p0, float p1, float p2,
    float q0, float q1, float q2,
    float m00, float m01, float m02,
    float m10, float m11, float m12,
    float m20, float m21, float m22,
    float b0, float b1, float b2,
    float zeps, float sf,
    float& a0o, float& a1o, float& a2o)
{
    float c0 = m00 * q0 + m01 * q1 + m02 * q2;
    float c1 = m10 * q0 + m11 * q1 + m12 * q2;
    float c2 = m20 * q0 + m21 * q1 + m22 * q2;
    sparsemax3(c0, c1, c2, c0, c1, c2);
    // Reference applies sparsemax to c twice; exactly idempotent projection,
    // second application changes ~ulp. Dropped.
    sparsemax3(p0, p1, p2, p0, p1, p2);
    float a0 = p0 + b0 * (c0 - p0);
    float a1 = p1 + b1 * (c1 - p1);
    float a2 = p2 + b2 * (c2 - p2);
    float z0 = fmaxf(p0 + c0, zeps);
    float z1 = fmaxf(p1 + c1, zeps);
    float z2 = fmaxf(p2 + c2, zeps);
    float rs = fast_rcp(z0 + z1 + z2);
    z0 *= rs; z1 *= rs; z2 *= rs;
    float ent = -(z0 * fast_ln(z0) + z1 * fast_ln(z1) + z2 * fast_ln(z2));
    float dot = p0 * c0 + p1 * c1 + p2 * c2;
    float pp = p0 * p0 + p1 * p1 + p2 * p2;
    float cc = c0 * c0 + c1 * c1 + c2 * c2;
    float cosv = 0.1f + dot * fast_rsq(fmaxf(pp * cc, 1e-20f));
    float scale = sf * cosv * fast_rcp(ent);
    a0o = fmaxf(a0 * scale, 0.001f);
    a1o = fmaxf(a1 * scale, 0.001f);
    a2o = fmaxf(a2 * scale, 0.001f);
}

// 8 edges/thread: quad t via LDS-DMA (dense), quad t+nT direct-to-VGPR.
// 14 VMEM ops in flight per wave (vs 7 in rounds 0-9) at UNCHANGED
// occupancy (LDS 24 KB/block -> ~16 waves/CU, same as round 6).
// __launch_bounds__(256,4): 4 waves/EU -> VGPR cap 128, matches LDS limit.
__global__ __launch_bounds__(BLOCK, 4) void alpha_kernel(
    const float* __restrict__ prnt, const float* __restrict__ child,
    const float* __restrict__ Mg, const float* __restrict__ betag,
    const float* __restrict__ zeps_p, const float* __restrict__ sf_p,
    const int* __restrict__ rels, float* __restrict__ out, int n_edges)
{
    // Per-wave private staging (first-half quads only): wave w owns
    // sP[w*768..] / sC[w*768..], 3 KB each. No __syncthreads anywhere.
    __shared__ __align__(16) float sP[NWAVES * 768];
    __shared__ __align__(16) float sC[NWAVES * 768];

    const int tid  = threadIdx.x;
    const int lane = tid & 63;
    const int w    = tid >> 6;

    // Lane-resident parameter table: lane l holds M[l] (9 regs) + beta[l].
    // These are L1-hit after the first waves; they retire fast.
    float mt[9], bt[3];
    {
        const float* mr = Mg + lane * 9;
#pragma unroll
        for (int k = 0; k < 9; ++k) mt[k] = mr[k];
        const float* br = betag + lane * 3;
#pragma unroll
        for (int k = 0; k < 3; ++k) bt[k] = br[k];
    }

    const float zeps = zeps_p[0];
    const float sf   = sf_p[0];
    const int nQ = n_edges >> 2;             // total full quads (4 edges)
    const int nT = nQ >> 1;                  // threads: 2 quads each

    if (nT > 0) {
        const int t   = blockIdx.x * BLOCK + tid;
        const int tc  = min(t, nT - 1);      // clamp: bpermute needs all lanes
        const int wt0 = blockIdx.x * BLOCK + (w << 6);   // wave's thread 0
        const int F1  = 3 * nT;              // float4 count of first half
        const int qd  = tc + nT;             // this thread's direct quad

        float* lp = &sP[w * 768];
        float* lc = &sC[w * 768];

        // ====== issue ALL 14 VMEM ops back-to-back, drain ONCE ======
        // 2 rels loads (VGPR)
        const int4* r4p = (const int4*)rels;
        int4 ra = r4p[tc];
        int4 rd = r4p[qd];
        // 6 dense LDS-DMAs for the wave's first-half window (16 lines each)
#pragma unroll
        for (int j = 0; j < 3; ++j) {
            int g = min(3 * wt0 + j * 64 + lane, F1 - 1);
            gload_lds16(prnt  + 4 * g, lp + j * 256);
            gload_lds16(child + 4 * g, lc + j * 256);
        }
        // 6 direct strided loads for the second-half quad
        const f32x4* p4 = (const f32x4*)prnt;
        const f32x4* c4 = (const f32x4*)child;
        f32x4 dpa = p4[3 * qd], dpb = p4[3 * qd + 1], dpc = p4[3 * qd + 2];
        f32x4 dca = c4[3 * qd], dcb = c4[3 * qd + 1], dcc = c4[3 * qd + 2];

        asm volatile("s_waitcnt vmcnt(0)" ::: "memory");

        // ---- direct half first (consumes the 24 direct VGPRs early) ----
        {
            float P[12] = {dpa.x, dpa.y, dpa.z, dpa.w, dpb.x, dpb.y, dpb.z,
                           dpb.w, dpc.x, dpc.y, dpc.z, dpc.w};
            float C[12] = {dca.x, dca.y, dca.z, dca.w, dcb.x, dcb.y, dcb.z,
                           dcb.w, dcc.x, dcc.y, dcc.z, dcc.w};
            int R[4] = {rd.x, rd.y, rd.z, rd.w};
            float O[12];
#pragma unroll
            for (int e = 0; e < 4; ++e) {
                int ab = R[e] << 2;
                float g0 = bperm(ab, mt[0]), g1 = bperm(ab, mt[1]), g2 = bperm(ab, mt[2]);
                float g3 = bperm(ab, mt[3]), g4 = bperm(ab, mt[4]), g5 = bperm(ab, mt[5]);
                float g6 = bperm(ab, mt[6]), g7 = bperm(ab, mt[7]), g8 = bperm(ab, mt[8]);
                float h0 = bperm(ab, bt[0]), h1 = bperm(ab, bt[1]), h2 = bperm(ab, bt[2]);
                edge_core(P[3 * e], P[3 * e + 1], P[3 * e + 2],
                          C[3 * e], C[3 * e + 1], C[3 * e + 2],
                          g0, g1, g2, g3, g4, g5, g6, g7, g8,
                          h0, h1, h2, zeps, sf,
                          O[3 * e], O[3 * e + 1], O[3 * e + 2]);
            }
            if (t < nT) {                    // strided stores, direct half
                f32x4* o4 = (f32x4*)out;
                o4[3 * qd]     = f32x4{O[0], O[1], O[2],  O[3]};
                o4[3 * qd + 1] = f32x4{O[4], O[5], O[6],  O[7]};
                o4[3 * qd + 2] = f32x4{O[8], O[9], O[10], O[11]};
            }
        }

        // ---- LDS half (round-6 structure verbatim) ----
        f32x4 pa = *(const f32x4*)(lp + lane * 12);
        f32x4 pb = *(const f32x4*)(lp + lane * 12 + 4);
        f32x4 pc = *(const f32x4*)(lp + lane * 12 + 8);
        f32x4 ca = *(const f32x4*)(lc + lane * 12);
        f32x4 cb = *(const f32x4*)(lc + lane * 12 + 4);
        f32x4 cc = *(const f32x4*)(lc + lane * 12 + 8);
        {
            float P[12] = {pa.x, pa.y, pa.z, pa.w, pb.x, pb.y, pb.z, pb.w,
                           pc.x, pc.y, pc.z, pc.w};
            float C[12] = {ca.x, ca.y, ca.z, ca.w, cb.x, cb.y, cb.z, cb.w,
                           cc.x, cc.y, cc.z, cc.w};
            int R[4] = {ra.x, ra.y, ra.z, ra.w};
            float O[12];
#pragma unroll
            for (int e = 0; e < 4; ++e) {
                int ab = R[e] << 2;
                float g0 = bperm(ab, mt[0]), g1 = bperm(ab, mt[1]), g2 = bperm(ab, mt[2]);
                float g3 = bperm(ab, mt[3]), g4 = bperm(ab, mt[4]), g5 = bperm(ab, mt[5]);
                float g6 = bperm(ab, mt[6]), g7 = bperm(ab, mt[7]), g8 = bperm(ab, mt[8]);
                float h0 = bperm(ab, bt[0]), h1 = bperm(ab, bt[1]), h2 = bperm(ab, bt[2]);
                edge_core(P[3 * e], P[3 * e + 1], P[3 * e + 2],
                          C[3 * e], C[3 * e + 1], C[3 * e + 2],
                          g0, g1, g2, g3, g4, g5, g6, g7, g8,
                          h0, h1, h2, zeps, sf,
                          O[3 * e], O[3 * e + 1], O[3 * e + 2]);
            }
            // Transpose through the dead sP region: each lane writes ONLY
            // its own 48 B slot (the one it just read) — no cross-lane WAR.
            *(f32x4*)(lp + lane * 12)     = f32x4{O[0], O[1], O[2],  O[3]};
            *(f32x4*)(lp + lane * 12 + 4) = f32x4{O[4], O[5], O[6],  O[7]};
            *(f32x4*)(lp + lane * 12 + 8) = f32x4{O[8], O[9], O[10], O[11]};
        }
        asm volatile("s_waitcnt lgkmcnt(0)" ::: "memory");

        // Dense stores for the LDS half. Guard g < F1 excludes exactly the
        // slots owned by clamped (t >= nT) threads.
#pragma unroll
        for (int j = 0; j < 3; ++j) {
            int g = 3 * wt0 + j * 64 + lane;
            if (g < F1) {
                f32x4 v = *(const f32x4*)(lp + j * 256 + lane * 4);
                *(f32x4*)(out + 4 * g) = v;
            }
        }
    }

    // Defensive scalar tail for n_edges % 8 (none at N=8M). Divergent:
    // no cross-lane ops — read M/beta straight from global.
    if (blockIdx.x == 0 && threadIdx.x == 0) {
        for (int e = (n_edges >> 3) * 8; e < n_edges; ++e) {
            int r = rels[e];
            const float* m = Mg + r * 9;
            const float* b = betag + r * 3;
            float a0, a1, a2;
            edge_core(prnt[3 * e], prnt[3 * e + 1], prnt[3 * e + 2],
                      child[3 * e], child[3 * e + 1], child[3 * e + 2],
                      m[0], m[1], m[2], m[3], m[4], m[5], m[6], m[7], m[8],
                      b[0], b[1], b[2], zeps, sf, a0, a1, a2);
            out[3 * e] = a0; out[3 * e + 1] = a1; out[3 * e + 2] = a2;
        }
    }
}

extern "C" void kernel_launch(void* const* d_in, const int* in_sizes, int n_in,
                              void* d_out, int out_size, void* d_ws, size_t ws_size,
                              hipStream_t stream) {
    const float* prnt  = (const float*)d_in[0];
    const float* child = (const float*)d_in[1];
    const float* Mg    = (const float*)d_in[2];
    const float* betag = (const float*)d_in[3];
    const float* zeps  = (const float*)d_in[4];
    const float* sf    = (const float*)d_in[5];
    const int*   rels  = (const int*)d_in[6];
    float* out = (float*)d_out;

    int n_edges = in_sizes[0] / 3;
    int nT = n_edges >> 3;                   // 8 edges per thread
    int nblocks = (nT + BLOCK - 1) / BLOCK;
    if (nblocks < 1) nblocks = 1;            // tail-only case
    alpha_kernel<<<nblocks, BLOCK, 0, stream>>>(
        prnt, child, Mg, betag, zeps, sf, rels, out, n_edges);
}